// Round 1
// baseline (157.165 us; speedup 1.0000x reference)
//
#include <hip/hip_runtime.h>
#include <limits.h>

#define ID_MAX 4096

// ---------------------------------------------------------------------------
// Init: first-occurrence table -> INT_MAX, graph_outputs -> 0
// ---------------------------------------------------------------------------
__global__ void init_kernel(int* __restrict__ table, float* __restrict__ graph_out,
                            int table_n, int graph_n) {
    int i = blockIdx.x * blockDim.x + threadIdx.x;
    if (i < table_n) table[i] = INT_MAX;
    if (i < graph_n) graph_out[i] = 0.0f;
}

// ---------------------------------------------------------------------------
// Build per-graph first-occurrence table: table[b][id] = min local pos m
// ---------------------------------------------------------------------------
__global__ void build_table_kernel(const int* __restrict__ node_index,
                                   const int* __restrict__ ptr,
                                   int* __restrict__ table, int N, int B) {
    int i = blockIdx.x * blockDim.x + threadIdx.x;
    if (i >= N) return;
    if (i < ptr[0] || i >= ptr[B]) return;   // dropped by segment_sum semantics
    // binary search: largest b with ptr[b] <= i
    int lo = 0, hi = B;
    while (hi - lo > 1) {
        int mid = (lo + hi) >> 1;
        if (ptr[mid] <= i) lo = mid; else hi = mid;
    }
    int b = lo;
    int m = i - ptr[b];                      // local position in graph b
    int id = node_index[i];
    if (id >= 0 && id < ID_MAX)
        atomicMin(&table[b * ID_MAX + id], m);
}

// ---------------------------------------------------------------------------
// Segment-sum pool: each block sums a chunk of rows, one thread per column.
// Run-length accumulate per graph; flush with atomicAdd at boundaries.
// (A 128-row chunk crosses at most one graph boundary when graphs >= 128 rows,
//  and the generic loop handles any ptr.)
// ---------------------------------------------------------------------------
__global__ void pool_kernel(const float* __restrict__ x,
                            const int* __restrict__ ptr,
                            float* __restrict__ graph_out,
                            int N, int B, int D, int rows_per_block) {
    int d = threadIdx.x;                     // blockDim.x == D
    int r0 = blockIdx.x * rows_per_block;
    int r1 = min(r0 + rows_per_block, N);

    float acc = 0.0f;
    int accb = -1;
    for (int i = r0; i < r1; ++i) {
        int b = -1;
        if (i >= ptr[0] && i < ptr[B]) {
            int lo = 0, hi = B;
            while (hi - lo > 1) {
                int mid = (lo + hi) >> 1;
                if (ptr[mid] <= i) lo = mid; else hi = mid;
            }
            b = lo;
        }
        if (b != accb) {
            if (accb >= 0 && acc != 0.0f)
                atomicAdd(&graph_out[(size_t)accb * D + d], acc);
            acc = 0.0f;
            accb = b;
        }
        if (b >= 0) acc += x[(size_t)i * D + d];
    }
    if (accb >= 0)
        atomicAdd(&graph_out[(size_t)accb * D + d], acc);
}

// ---------------------------------------------------------------------------
// Gather: one float4 of the [B,L,D] output per thread.
// seq_out[b,l,:] = (table hit m) ? x[m,:] : 0    (row m used GLOBALLY --
// faithful to the reference's local-index-as-global-row behavior)
// ---------------------------------------------------------------------------
__global__ void gather4_kernel(const int* __restrict__ input_ids,
                               const int* __restrict__ table,
                               const float4* __restrict__ x4,
                               float4* __restrict__ seq_out4,
                               long long total_vec, int vec_per_row, int L) {
    long long t = (long long)blockIdx.x * blockDim.x + threadIdx.x;
    if (t >= total_vec) return;
    int row = (int)(t / vec_per_row);        // flattened (b,l)
    int c   = (int)(t - (long long)row * vec_per_row);
    int b   = row / L;
    int id  = input_ids[row];
    int m   = table[b * ID_MAX + id];
    float4 v = make_float4(0.f, 0.f, 0.f, 0.f);
    if (m != INT_MAX)
        v = x4[(long long)m * vec_per_row + c];
    seq_out4[t] = v;
}

// Scalar fallback (only used if D % 4 != 0)
__global__ void gather1_kernel(const int* __restrict__ input_ids,
                               const int* __restrict__ table,
                               const float* __restrict__ x,
                               float* __restrict__ seq_out,
                               long long total, int D, int L) {
    long long t = (long long)blockIdx.x * blockDim.x + threadIdx.x;
    if (t >= total) return;
    long long row = t / D;
    int c = (int)(t - row * D);
    int b = (int)(row / L);
    int id = input_ids[row];
    int m  = table[b * ID_MAX + id];
    seq_out[t] = (m != INT_MAX) ? x[(long long)m * D + c] : 0.0f;
}

extern "C" void kernel_launch(void* const* d_in, const int* in_sizes, int n_in,
                              void* d_out, int out_size, void* d_ws, size_t ws_size,
                              hipStream_t stream) {
    const int*   input_ids  = (const int*)  d_in[0];   // [B, L]
    const int*   node_index = (const int*)  d_in[1];   // [N]
    const float* x          = (const float*)d_in[2];   // [N, D]
    const int*   ptr        = (const int*)  d_in[3];   // [B+1]

    const int BL = in_sizes[0];
    const int N  = in_sizes[1];
    const int D  = in_sizes[2] / N;
    const int B  = in_sizes[3] - 1;
    const int L  = BL / B;

    float* seq_out   = (float*)d_out;                    // [B*L*D]
    float* graph_out = (float*)d_out + (size_t)BL * D;   // [B*D]
    int*   table     = (int*)d_ws;                       // [B * ID_MAX]

    const int table_n = B * ID_MAX;
    const int graph_n = B * D;
    const int init_n  = table_n > graph_n ? table_n : graph_n;

    init_kernel<<<(init_n + 255) / 256, 256, 0, stream>>>(table, graph_out,
                                                          table_n, graph_n);

    build_table_kernel<<<(N + 255) / 256, 256, 0, stream>>>(node_index, ptr,
                                                            table, N, B);

    const int rows_per_block = 128;
    const int nchunks = (N + rows_per_block - 1) / rows_per_block;
    pool_kernel<<<nchunks, D, 0, stream>>>(x, ptr, graph_out, N, B, D,
                                           rows_per_block);

    if ((D & 3) == 0) {
        const int vec_per_row = D >> 2;
        const long long total_vec = (long long)BL * vec_per_row;
        const int blocks = (int)((total_vec + 255) / 256);
        gather4_kernel<<<blocks, 256, 0, stream>>>(input_ids, table,
                                                   (const float4*)x,
                                                   (float4*)seq_out,
                                                   total_vec, vec_per_row, L);
    } else {
        const long long total = (long long)BL * D;
        const int blocks = (int)((total + 255) / 256);
        gather1_kernel<<<blocks, 256, 0, stream>>>(input_ids, table, x,
                                                   seq_out, total, D, L);
    }
}

// Round 2
// 104.159 us; speedup vs baseline: 1.5089x; 1.5089x over previous
//
#include <hip/hip_runtime.h>
#include <limits.h>

#define ID_MAX 4096
#define POOL_ROWS 64

// ---------------------------------------------------------------------------
// Init: first-occurrence table -> INT_MAX, graph_outputs -> 0
// ---------------------------------------------------------------------------
__global__ void init_kernel(int* __restrict__ table, float* __restrict__ graph_out,
                            int table_n, int graph_n) {
    int i = blockIdx.x * blockDim.x + threadIdx.x;
    if (i < table_n) table[i] = INT_MAX;
    if (i < graph_n) graph_out[i] = 0.0f;
}

// ---------------------------------------------------------------------------
// Build per-graph first-occurrence table: table[b][id] = min local pos m
// ---------------------------------------------------------------------------
__global__ void build_table_kernel(const int* __restrict__ node_index,
                                   const int* __restrict__ ptr,
                                   int* __restrict__ table, int N, int B) {
    __shared__ int sptr[64];
    if (threadIdx.x <= B) sptr[threadIdx.x] = ptr[threadIdx.x];
    __syncthreads();
    int i = blockIdx.x * blockDim.x + threadIdx.x;
    if (i >= N) return;
    if (i < sptr[0] || i >= sptr[B]) return;   // dropped by segment_sum semantics
    int lo = 0, hi = B;
    while (hi - lo > 1) {
        int mid = (lo + hi) >> 1;
        if (sptr[mid] <= i) lo = mid; else hi = mid;
    }
    int b = lo;
    int m = i - sptr[b];                       // local position in graph b
    int id = node_index[i];
    if (id >= 0 && id < ID_MAX)
        atomicMin(&table[b * ID_MAX + id], m);
}

// ---------------------------------------------------------------------------
// Segment-sum pool, float4-vectorized.
// Block = 256 threads: c = tid % vpr (vec column), rsub = tid / vpr (row lane).
// Each block covers POOL_ROWS rows. ptr cached in LDS; if the whole chunk is
// inside one graph (common case: graphs ~1500 rows), the hot loop is pure
// independent float4 load+add (pipelineable), then LDS-reduce row lanes and
// one atomicAdd x4 per vec column. Boundary chunks take the generic path.
// ---------------------------------------------------------------------------
__device__ __forceinline__ int seg_search(const int* sptr, int B, int i) {
    if (i < sptr[0] || i >= sptr[B]) return -1;
    int lo = 0, hi = B;
    while (hi - lo > 1) {
        int mid = (lo + hi) >> 1;
        if (sptr[mid] <= i) lo = mid; else hi = mid;
    }
    return lo;
}

__global__ void pool4_kernel(const float4* __restrict__ x4,
                             const int* __restrict__ ptr,
                             float* __restrict__ graph_out,
                             int N, int B, int D, int vpr) {
    __shared__ int sptr[64];
    __shared__ float4 red[256];
    int tid = threadIdx.x;
    if (tid <= B) sptr[tid] = ptr[tid];
    __syncthreads();

    int rows_per_iter = 256 / vpr;             // vpr divides 256 (checked host-side)
    int c    = tid % vpr;
    int rsub = tid / vpr;

    int r0 = blockIdx.x * POOL_ROWS;
    int r1 = min(r0 + POOL_ROWS, N);

    int b_first = seg_search(sptr, B, r0);
    int b_last  = seg_search(sptr, B, r1 - 1);

    if (b_first == b_last && b_first >= 0) {
        // ---- fast path: single segment, pure streaming ----
        float4 acc = make_float4(0.f, 0.f, 0.f, 0.f);
        for (int i = r0 + rsub; i < r1; i += rows_per_iter) {
            float4 v = x4[(size_t)i * vpr + c];
            acc.x += v.x; acc.y += v.y; acc.z += v.z; acc.w += v.w;
        }
        red[tid] = acc;
        __syncthreads();
        if (rsub == 0) {
            for (int k = 1; k < rows_per_iter; ++k) {
                float4 v = red[k * vpr + c];
                acc.x += v.x; acc.y += v.y; acc.z += v.z; acc.w += v.w;
            }
            float* dst = &graph_out[(size_t)b_first * D + c * 4];
            atomicAdd(dst + 0, acc.x);
            atomicAdd(dst + 1, acc.y);
            atomicAdd(dst + 2, acc.z);
            atomicAdd(dst + 3, acc.w);
        }
    } else {
        // ---- generic path: chunk crosses a boundary (rare) ----
        float4 acc = make_float4(0.f, 0.f, 0.f, 0.f);
        int accb = -1;
        for (int i = r0 + rsub; i < r1; i += rows_per_iter) {
            int b = seg_search(sptr, B, i);
            if (b != accb) {
                if (accb >= 0) {
                    float* dst = &graph_out[(size_t)accb * D + c * 4];
                    atomicAdd(dst + 0, acc.x);
                    atomicAdd(dst + 1, acc.y);
                    atomicAdd(dst + 2, acc.z);
                    atomicAdd(dst + 3, acc.w);
                }
                acc = make_float4(0.f, 0.f, 0.f, 0.f);
                accb = b;
            }
            if (b >= 0) {
                float4 v = x4[(size_t)i * vpr + c];
                acc.x += v.x; acc.y += v.y; acc.z += v.z; acc.w += v.w;
            }
        }
        if (accb >= 0) {
            float* dst = &graph_out[(size_t)accb * D + c * 4];
            atomicAdd(dst + 0, acc.x);
            atomicAdd(dst + 1, acc.y);
            atomicAdd(dst + 2, acc.z);
            atomicAdd(dst + 3, acc.w);
        }
    }
}

// Scalar fallback pool (D % 4 != 0 or vpr doesn't divide 256)
__global__ void pool1_kernel(const float* __restrict__ x,
                             const int* __restrict__ ptr,
                             float* __restrict__ graph_out,
                             int N, int B, int D, int rows_per_block) {
    __shared__ int sptr[64];
    if (threadIdx.x <= B) sptr[threadIdx.x] = ptr[threadIdx.x];
    __syncthreads();
    int d = threadIdx.x;
    if (d >= D) return;
    int r0 = blockIdx.x * rows_per_block;
    int r1 = min(r0 + rows_per_block, N);
    float acc = 0.0f;
    int accb = -1;
    for (int i = r0; i < r1; ++i) {
        int b = seg_search(sptr, B, i);
        if (b != accb) {
            if (accb >= 0) atomicAdd(&graph_out[(size_t)accb * D + d], acc);
            acc = 0.0f; accb = b;
        }
        if (b >= 0) acc += x[(size_t)i * D + d];
    }
    if (accb >= 0) atomicAdd(&graph_out[(size_t)accb * D + d], acc);
}

// ---------------------------------------------------------------------------
// Gather: one float4 of the [B,L,D] output per thread.
// seq_out[b,l,:] = (table hit m) ? x[m,:] : 0    (row m used GLOBALLY --
// faithful to the reference's local-index-as-global-row behavior)
// ---------------------------------------------------------------------------
__global__ void gather4_kernel(const int* __restrict__ input_ids,
                               const int* __restrict__ table,
                               const float4* __restrict__ x4,
                               float4* __restrict__ seq_out4,
                               long long total_vec, int vec_per_row, int L) {
    long long t = (long long)blockIdx.x * blockDim.x + threadIdx.x;
    if (t >= total_vec) return;
    int row = (int)(t / vec_per_row);        // flattened (b,l)
    int c   = (int)(t - (long long)row * vec_per_row);
    int b   = row / L;
    int id  = input_ids[row];
    int m   = table[b * ID_MAX + id];
    float4 v = make_float4(0.f, 0.f, 0.f, 0.f);
    if (m != INT_MAX)
        v = x4[(long long)m * vec_per_row + c];
    seq_out4[t] = v;
}

// Scalar fallback (only used if D % 4 != 0)
__global__ void gather1_kernel(const int* __restrict__ input_ids,
                               const int* __restrict__ table,
                               const float* __restrict__ x,
                               float* __restrict__ seq_out,
                               long long total, int D, int L) {
    long long t = (long long)blockIdx.x * blockDim.x + threadIdx.x;
    if (t >= total) return;
    long long row = t / D;
    int c = (int)(t - row * D);
    int b = (int)(row / L);
    int id = input_ids[row];
    int m  = table[b * ID_MAX + id];
    seq_out[t] = (m != INT_MAX) ? x[(long long)m * D + c] : 0.0f;
}

extern "C" void kernel_launch(void* const* d_in, const int* in_sizes, int n_in,
                              void* d_out, int out_size, void* d_ws, size_t ws_size,
                              hipStream_t stream) {
    const int*   input_ids  = (const int*)  d_in[0];   // [B, L]
    const int*   node_index = (const int*)  d_in[1];   // [N]
    const float* x          = (const float*)d_in[2];   // [N, D]
    const int*   ptr        = (const int*)  d_in[3];   // [B+1]

    const int BL = in_sizes[0];
    const int N  = in_sizes[1];
    const int D  = in_sizes[2] / N;
    const int B  = in_sizes[3] - 1;
    const int L  = BL / B;

    float* seq_out   = (float*)d_out;                    // [B*L*D]
    float* graph_out = (float*)d_out + (size_t)BL * D;   // [B*D]
    int*   table     = (int*)d_ws;                       // [B * ID_MAX]

    const int table_n = B * ID_MAX;
    const int graph_n = B * D;
    const int init_n  = table_n > graph_n ? table_n : graph_n;

    init_kernel<<<(init_n + 255) / 256, 256, 0, stream>>>(table, graph_out,
                                                          table_n, graph_n);

    build_table_kernel<<<(N + 255) / 256, 256, 0, stream>>>(node_index, ptr,
                                                            table, N, B);

    const int vpr = D >> 2;                  // float4 per row
    const bool vec_ok = ((D & 3) == 0) && (vpr > 0) && (vpr <= 256) &&
                        (256 % vpr == 0) && (B <= 63);
    if (vec_ok) {
        const int nchunks = (N + POOL_ROWS - 1) / POOL_ROWS;
        pool4_kernel<<<nchunks, 256, 0, stream>>>((const float4*)x, ptr,
                                                  graph_out, N, B, D, vpr);
    } else {
        const int rows_per_block = 128;
        const int nchunks = (N + rows_per_block - 1) / rows_per_block;
        int bs = D < 1024 ? ((D + 63) / 64) * 64 : 1024;
        pool1_kernel<<<nchunks, bs, 0, stream>>>(x, ptr, graph_out, N, B, D,
                                                 rows_per_block);
    }

    if ((D & 3) == 0) {
        const long long total_vec = (long long)BL * vpr;
        const int blocks = (int)((total_vec + 255) / 256);
        gather4_kernel<<<blocks, 256, 0, stream>>>(input_ids, table,
                                                   (const float4*)x,
                                                   (float4*)seq_out,
                                                   total_vec, vpr, L);
    } else {
        const long long total = (long long)BL * D;
        const int blocks = (int)((total + 255) / 256);
        gather1_kernel<<<blocks, 256, 0, stream>>>(input_ids, table, x,
                                                   seq_out, total, D, L);
    }
}